// Round 4
// baseline (25732.654 us; speedup 1.0000x reference)
//
#include <hip/hip_runtime.h>
#include <cstddef>

// Problem constants
#define Bsz  4096
#define Sseq 16
#define Gdim 128
#define Edim 256
#define Hdim 512
#define H4   2048
#define Psteps 16
#define BK   16

// ---------------------------------------------------------------------------
// Fold kernel.
//  - encE/decE = (Wih @ emb_W) with GATE-INTERLEAVED rows: out row c = j*4+gate
//  - encWhhI/decWhhI = Whh rows reordered to the same interleaving
//  - encBI/decBI = biases interleaved; v0bI = dec bias + dec_Wih@dec_input0
// ---------------------------------------------------------------------------
__global__ void fold_kernel(const float* __restrict__ encWih,
                            const float* __restrict__ encWhh,
                            const float* __restrict__ enc_b,
                            const float* __restrict__ decWih,
                            const float* __restrict__ decWhh,
                            const float* __restrict__ dec_b,
                            const float* __restrict__ embW,
                            const float* __restrict__ dec0,
                            float* __restrict__ encE, float* __restrict__ encWhhI,
                            float* __restrict__ encBI,
                            float* __restrict__ decE, float* __restrict__ decWhhI,
                            float* __restrict__ decBI, float* __restrict__ v0bI) {
    const int o = blockIdx.x;            // original row 0..2047 (gate*512 + j)
    const int gate = o >> 9, j = o & 511;
    const int c = j * 4 + gate;          // interleaved row
    const int g = threadIdx.x;           // 0..127
    float se = 0.f, sd = 0.f;
    for (int e = 0; e < Edim; ++e) {
        float w = embW[e * Gdim + g];
        se += encWih[(size_t)o * Edim + e] * w;
        sd += decWih[(size_t)o * Edim + e] * w;
    }
    encE[(size_t)c * Gdim + g] = se;
    decE[(size_t)c * Gdim + g] = sd;
    for (int k = g; k < Hdim; k += Gdim) {
        encWhhI[(size_t)c * Hdim + k] = encWhh[(size_t)o * Hdim + k];
        decWhhI[(size_t)c * Hdim + k] = decWhh[(size_t)o * Hdim + k];
    }
    if (g == 0) {
        encBI[c] = enc_b[o];
        decBI[c] = dec_b[o];
        float s = dec_b[o];
        for (int e = 0; e < Edim; ++e) s += decWih[(size_t)o * Edim + e] * dec0[e];
        v0bI[c] = s;
    }
}

// ---------------------------------------------------------------------------
// Big fused GEMM + LSTM epilogue. 128 threads = 2 waves, block tile 128x128.
// Each wave: 128 rows x 64 cols; lane 8x8 grid; per-lane tile 16x8 where the
// 16 rows are split 8+8 at offset +64 (LDS read addresses stride 8 -> 2-way
// bank alias only, which is free; contiguous 16 would be 4-way conflicted).
// LDS/VALU per wave per kk: 6 ds_read_b128 (72cy) vs 128 FMA (256cy) -> ~89%
// VALU ceiling (the round-3 8x4 tile was capped at 44-65%).
// Main cols (< split): gates GEMM (A1 gathered x-part + A2 h-part) with the
// LSTM gate epilogue writing h_out/c_out. Aux cols (>= split): K2-only GEMM
// h @ W3^T + bias3 -> C3 (the hoisted Wref2 projection into u2).
// ---------------------------------------------------------------------------
__global__ __launch_bounds__(128, 2) void gemm_big(
    const float* __restrict__ A1, int lda1, int K1,
    const float* __restrict__ W1,
    const int* __restrict__ gather, int gmul,
    const float* __restrict__ A2, int lda2, int K2,
    const float* __restrict__ W2,
    const float* __restrict__ bias,
    int split,
    const float* __restrict__ W3, const float* __restrict__ bias3,
    float* __restrict__ C3, int ldc3,
    const float* __restrict__ c_in, float* __restrict__ h_out,
    float* __restrict__ c_out, int czero)
{
    __shared__ float As[BK][128];
    __shared__ float Bs[BK][128];
    const int tid = threadIdx.x;
    const int rowBase = blockIdx.y * 128;
    const int colBase = blockIdx.x * 128;
    const bool aux = (colBase >= split);

    const int wv = tid >> 6;
    const int lane = tid & 63;
    const int lx = lane & 7, ly = lane >> 3;
    const int cOff = wv * 64 + lx * 8;
    const int rA = ly * 8;              // rows rA..rA+7 and rA+64..rA+71

    // loop-invariant row pointers (one row per thread for staging)
    size_t g0 = 0;
    if (gather) g0 = (size_t)gather[rowBase + tid] * gmul;
    const float* arow1 = A1 ? (A1 + (size_t)(rowBase + tid) * lda1 + g0) : nullptr;
    const float* arow2 = A2 ? (A2 + (size_t)(rowBase + tid) * lda2) : nullptr;
    const float* brow1 = W1 ? (W1 + (size_t)(colBase + tid) * K1) : nullptr;
    const float* brow2 = W2 ? (W2 + (size_t)(colBase + tid) * K2) : nullptr;
    const float* brow3 = (aux && W3) ? (W3 + (size_t)(colBase - split + tid) * K2)
                                     : nullptr;

    float4 aR[4], bR[4];
    auto stageA = [&](int kt) {
        const float* p = (kt < K1) ? (arow1 + kt) : (arow2 + (kt - K1));
#pragma unroll
        for (int q = 0; q < 4; ++q) aR[q] = *(const float4*)(p + 4 * q);
    };
    auto stageB = [&](int kt) {
        const float* p;
        if (aux)          p = brow3 + (kt - K1);
        else if (kt < K1) p = brow1 + kt;
        else              p = brow2 + (kt - K1);
#pragma unroll
        for (int q = 0; q < 4; ++q) bR[q] = *(const float4*)(p + 4 * q);
    };

    float acc[16][8];
#pragma unroll
    for (int i = 0; i < 16; ++i)
#pragma unroll
        for (int j = 0; j < 8; ++j) acc[i][j] = 0.f;

    const int KT = K1 + K2;
    const int kt0 = aux ? K1 : 0;
    stageA(kt0); stageB(kt0);

    for (int kt = kt0; kt < KT; kt += BK) {
        __syncthreads();
#pragma unroll
        for (int q = 0; q < 4; ++q) {
            As[4 * q + 0][tid] = aR[q].x;
            As[4 * q + 1][tid] = aR[q].y;
            As[4 * q + 2][tid] = aR[q].z;
            As[4 * q + 3][tid] = aR[q].w;
            Bs[4 * q + 0][tid] = bR[q].x;
            Bs[4 * q + 1][tid] = bR[q].y;
            Bs[4 * q + 2][tid] = bR[q].z;
            Bs[4 * q + 3][tid] = bR[q].w;
        }
        __syncthreads();
        if (kt + BK < KT) { stageA(kt + BK); stageB(kt + BK); }

#pragma unroll
        for (int kk = 0; kk < BK; ++kk) {
            float a[16], b[8];
            *(float4*)&a[0]  = *(const float4*)&As[kk][rA];
            *(float4*)&a[4]  = *(const float4*)&As[kk][rA + 4];
            *(float4*)&a[8]  = *(const float4*)&As[kk][rA + 64];
            *(float4*)&a[12] = *(const float4*)&As[kk][rA + 68];
            *(float4*)&b[0]  = *(const float4*)&Bs[kk][cOff];
            *(float4*)&b[4]  = *(const float4*)&Bs[kk][cOff + 4];
#pragma unroll
            for (int i = 0; i < 16; ++i)
#pragma unroll
                for (int j = 0; j < 8; ++j) acc[i][j] += a[i] * b[j];
        }
    }

    if (!aux) {
        // fused LSTM epilogue; cols are gate-interleaved: col = j*4 + gate
        float bb[8];
        *(float4*)&bb[0] = *(const float4*)(bias + colBase + cOff);
        *(float4*)&bb[4] = *(const float4*)(bias + colBase + cOff + 4);
        const int jBase = (colBase + cOff) >> 2;   // 2 j's per lane
#pragma unroll
        for (int i = 0; i < 16; ++i) {
            const int row = rowBase + ((i < 8) ? (rA + i) : (64 + rA + i - 8));
#pragma unroll
            for (int jj = 0; jj < 2; ++jj) {
                float gi = acc[i][jj * 4 + 0] + bb[jj * 4 + 0];
                float gf = acc[i][jj * 4 + 1] + bb[jj * 4 + 1];
                float gg = acc[i][jj * 4 + 2] + bb[jj * 4 + 2];
                float go = acc[i][jj * 4 + 3] + bb[jj * 4 + 3];
                float si = 1.f / (1.f + expf(-gi));
                float sf = 1.f / (1.f + expf(-gf));
                float so = 1.f / (1.f + expf(-go));
                const int j = jBase + jj;
                float co = czero ? 0.f : c_in[(size_t)row * Hdim + j];
                float cn = si * tanhf(gg) + sf * co;
                c_out[(size_t)row * Hdim + j] = cn;
                h_out[(size_t)row * Hdim + j] = so * tanhf(cn);
            }
        }
    } else {
        const int cb = colBase - split + cOff;
        float bb[8];
        *(float4*)&bb[0] = *(const float4*)(bias3 + cb);
        *(float4*)&bb[4] = *(const float4*)(bias3 + cb + 4);
#pragma unroll
        for (int i = 0; i < 16; ++i) {
            const int row = rowBase + ((i < 8) ? (rA + i) : (64 + rA + i - 8));
#pragma unroll
            for (int jj = 0; jj < 2; ++jj) {
                float4 o;
                o.x = acc[i][jj * 4 + 0] + bb[jj * 4 + 0];
                o.y = acc[i][jj * 4 + 1] + bb[jj * 4 + 1];
                o.z = acc[i][jj * 4 + 2] + bb[jj * 4 + 2];
                o.w = acc[i][jj * 4 + 3] + bb[jj * 4 + 3];
                *(float4*)(C3 + (size_t)row * ldc3 + cb + 4 * jj) = o;
            }
        }
    }
}

// ---------------------------------------------------------------------------
// Small GEMM for qp = h @ Wq2^T + bq2  (4096x512, K=512). 64x64 tile, 256
// threads, 2x2 waves, lane 8x8, per-lane 4x4 (round-3 proven config).
// ---------------------------------------------------------------------------
__global__ __launch_bounds__(256, 4) void gemm_qp(const float* __restrict__ A,
                                                  const float* __restrict__ W,
                                                  const float* __restrict__ bias,
                                                  float* __restrict__ C)
{
    __shared__ float As[BK][64];
    __shared__ float Bs[BK][64];
    const int tid = threadIdx.x;
    const int rowBase = blockIdx.y * 64;
    const int colBase = blockIdx.x * 64;
    const int wv = tid >> 6;
    const int waveX = wv & 1, waveY = wv >> 1;
    const int lane = tid & 63;
    const int lx = lane & 7, ly = lane >> 3;
    const int rOff = waveY * 32 + ly * 4;
    const int cOff = waveX * 32 + lx * 4;

    const int ra = tid & 63;
    const int ka = (tid >> 6) * 4;
    const float* arow = A + (size_t)(rowBase + ra) * Hdim + ka;
    const float* brow = W + (size_t)(colBase + ra) * Hdim + ka;

    float4 aR, bR;
    float acc[4][4];
#pragma unroll
    for (int i = 0; i < 4; ++i)
#pragma unroll
        for (int j = 0; j < 4; ++j) acc[i][j] = 0.f;

    aR = *(const float4*)(arow);
    bR = *(const float4*)(brow);
    for (int kt = 0; kt < Hdim; kt += BK) {
        __syncthreads();
        As[ka + 0][ra] = aR.x; As[ka + 1][ra] = aR.y;
        As[ka + 2][ra] = aR.z; As[ka + 3][ra] = aR.w;
        Bs[ka + 0][ra] = bR.x; Bs[ka + 1][ra] = bR.y;
        Bs[ka + 2][ra] = bR.z; Bs[ka + 3][ra] = bR.w;
        __syncthreads();
        if (kt + BK < Hdim) {
            aR = *(const float4*)(arow + kt + BK);
            bR = *(const float4*)(brow + kt + BK);
        }
#pragma unroll
        for (int kk = 0; kk < BK; ++kk) {
            float4 av = *(const float4*)&As[kk][rOff];
            float4 bv = *(const float4*)&Bs[kk][cOff];
            const float* ap = (const float*)&av;
            const float* bp = (const float*)&bv;
#pragma unroll
            for (int i = 0; i < 4; ++i)
#pragma unroll
                for (int j = 0; j < 4; ++j) acc[i][j] += ap[i] * bp[j];
        }
    }

    float4 bb = *(const float4*)(bias + colBase + cOff);
#pragma unroll
    for (int i = 0; i < 4; ++i) {
        const int row = rowBase + rOff + i;
        float4 o;
        o.x = acc[i][0] + bb.x;
        o.y = acc[i][1] + bb.y;
        o.z = acc[i][2] + bb.z;
        o.w = acc[i][3] + bb.w;
        *(float4*)(C + (size_t)row * Hdim + colBase + cOff) = o;
    }
}

// ---------------------------------------------------------------------------
// Attention + log-softmax + argmax + state update.
// ---------------------------------------------------------------------------
__global__ __launch_bounds__(256) void attn_step(const float* __restrict__ qp,
                                                 const float* __restrict__ u2,
                                                 const float* __restrict__ Vec2,
                                                 float* __restrict__ mask,
                                                 float* __restrict__ ll_ws,
                                                 int* __restrict__ nxt,
                                                 float* __restrict__ out_map,
                                                 float* __restrict__ out_ll,
                                                 int step, int node) {
    const int b = blockIdx.x;
    __shared__ float qpS[Hdim];
    __shared__ float vS[Hdim];
    __shared__ float logitS[Sseq];
    const int tid = threadIdx.x;
    qpS[tid]       = qp[(size_t)b * Hdim + tid];
    qpS[tid + 256] = qp[(size_t)b * Hdim + 256 + tid];
    vS[tid]        = Vec2[tid];
    vS[tid + 256]  = Vec2[256 + tid];
    __syncthreads();

    const int wave = tid >> 6, lane = tid & 63;
    for (int si = 0; si < 4; ++si) {
        int s = wave * 4 + si;
        const float* u2p = u2 + ((size_t)b * Sseq + s) * Hdim;
        float sum = 0.f;
#pragma unroll
        for (int i = 0; i < 8; ++i) {
            int hh = lane + i * 64;
            sum += vS[hh] * tanhf(qpS[hh] + u2p[hh]);
        }
        for (int off = 32; off > 0; off >>= 1) sum += __shfl_down(sum, off);
        if (lane == 0) {
            float pen = step ? mask[b * Sseq + s] * 1e8f : 0.f;
            logitS[s] = 10.f * sum - pen;
        }
    }
    __syncthreads();

    if (tid == 0) {
        float mx = logitS[0];
        int am = 0;
        for (int s = 1; s < Sseq; ++s)
            if (logitS[s] > mx) { mx = logitS[s]; am = s; }
        float se = 0.f;
        for (int s = 0; s < Sseq; ++s) se += expf(logitS[s] - mx);
        float lp = -logf(se);
        float llv = (step ? ll_ws[b] : 0.f) + lp;
        ll_ws[b] = llv;
        out_ll[b] = llv;
        nxt[b] = am;
        if (step == 0) {
            for (int s = 0; s < Sseq; ++s) mask[b * Sseq + s] = (s == am) ? 1.f : 0.f;
        } else {
            mask[b * Sseq + am] += 1.f;
        }
        out_map[b * Sseq + am] = (float)node;
    }
}

// ---------------------------------------------------------------------------
extern "C" void kernel_launch(void* const* d_in, const int* in_sizes, int n_in,
                              void* d_out, int out_size, void* d_ws, size_t ws_size,
                              hipStream_t stream) {
    const float* x       = (const float*)d_in[0];
    const float* emb_W   = (const float*)d_in[1];
    const float* enc_Wih = (const float*)d_in[2];
    const float* enc_Whh = (const float*)d_in[3];
    const float* enc_b   = (const float*)d_in[4];
    const float* dec_Wih = (const float*)d_in[5];
    const float* dec_Whh = (const float*)d_in[6];
    const float* dec_b   = (const float*)d_in[7];
    const float* Wq2     = (const float*)d_in[8];
    const float* bq2     = (const float*)d_in[9];
    const float* Wref2   = (const float*)d_in[10];
    const float* bref2   = (const float*)d_in[11];
    const float* Vec2    = (const float*)d_in[12];
    const float* dec0    = (const float*)d_in[13];

    // workspace layout (fp32 words) — ~187 MB
    float* ws      = (float*)d_ws;
    float* u2      = ws;                                   // B*S*H
    float* h0      = u2 + (size_t)Bsz * Sseq * Hdim;       // B*H each
    float* c0      = h0 + (size_t)Bsz * Hdim;
    float* h1      = c0 + (size_t)Bsz * Hdim;
    float* c1      = h1 + (size_t)Bsz * Hdim;
    float* qp      = c1 + (size_t)Bsz * Hdim;
    float* mask    = qp + (size_t)Bsz * Hdim;              // B*S
    float* ll      = mask + (size_t)Bsz * Sseq;            // B
    int*   nxt     = (int*)(ll + Bsz);                     // B
    float* encE    = (float*)(nxt + Bsz);                  // 2048*128
    float* decE    = encE + (size_t)H4 * Gdim;
    float* encWhhI = decE + (size_t)H4 * Gdim;             // 2048*512
    float* decWhhI = encWhhI + (size_t)H4 * Hdim;
    float* encBI   = decWhhI + (size_t)H4 * Hdim;          // 2048 each
    float* decBI   = encBI + H4;
    float* v0bI    = decBI + H4;

    float* out_map = (float*)d_out;                        // B*P floats
    float* out_ll  = out_map + (size_t)Bsz * Psteps;       // B floats

    static const int nodes[Psteps] = {0,0,0,0, 1,1,1,1, 2,2,2,2, 3,3,3,3};
    const int BIG = 1 << 30;

    fold_kernel<<<H4, Gdim, 0, stream>>>(enc_Wih, enc_Whh, enc_b,
                                         dec_Wih, dec_Whh, dec_b,
                                         emb_W, dec0,
                                         encE, encWhhI, encBI,
                                         decE, decWhhI, decBI, v0bI);

    // ---- encoder: 16 fused LSTM steps; step t>=1 also computes u2[t-1] ----
    for (int t = 0; t < Sseq; ++t) {
        float* ho = (t & 1) ? h0 : h1;
        float* co = (t & 1) ? c0 : c1;
        const float* hi = (t & 1) ? h1 : h0;
        const float* ci = (t & 1) ? c1 : c0;
        if (t == 0) {
            gemm_big<<<dim3(16, 32), 128, 0, stream>>>(
                x, Sseq * Gdim, Gdim, encE, nullptr, 0,
                nullptr, 0, 0, nullptr,
                encBI, BIG, nullptr, nullptr, nullptr, 0,
                co, ho, co, 1);
        } else {
            gemm_big<<<dim3(20, 32), 128, 0, stream>>>(
                x + t * Gdim, Sseq * Gdim, Gdim, encE, nullptr, 0,
                hi, Hdim, Hdim, encWhhI,
                encBI, H4, Wref2, bref2,
                u2 + (size_t)(t - 1) * Hdim, Sseq * Hdim,
                ci, ho, co, 0);
        }
    }

    // ---- decoder: 16 autoregressive steps; p=0 also computes u2[15] ----
    for (int p = 0; p < Psteps; ++p) {
        const int u = Sseq + p;
        float* ho = (u & 1) ? h0 : h1;
        float* co = (u & 1) ? c0 : c1;
        const float* hi = (u & 1) ? h1 : h0;
        const float* ci = (u & 1) ? c1 : c0;
        if (p == 0) {
            gemm_big<<<dim3(20, 32), 128, 0, stream>>>(
                nullptr, 0, 0, nullptr, nullptr, 0,
                hi, Hdim, Hdim, decWhhI,
                v0bI, H4, Wref2, bref2,
                u2 + (size_t)15 * Hdim, Sseq * Hdim,
                ci, ho, co, 0);
        } else {
            gemm_big<<<dim3(16, 32), 128, 0, stream>>>(
                x, Sseq * Gdim, Gdim, decE, nxt, Gdim,
                hi, Hdim, Hdim, decWhhI,
                decBI, BIG, nullptr, nullptr, nullptr, 0,
                ci, ho, co, 0);
        }
        gemm_qp<<<dim3(8, 64), 256, 0, stream>>>(ho, Wq2, bq2, qp);
        attn_step<<<Bsz, 256, 0, stream>>>(qp, u2, Vec2, mask, ll, nxt,
                                           out_map, out_ll, p, nodes[p]);
    }
}

// Round 5
// 6426.708 us; speedup vs baseline: 4.0040x; 4.0040x over previous
//
#include <hip/hip_runtime.h>
#include <cstddef>

// Problem constants
#define Bsz  4096
#define Sseq 16
#define Gdim 128
#define Edim 256
#define Hdim 512
#define H4   2048
#define Psteps 16
#define BK   16

// ---------------------------------------------------------------------------
// Fold kernel.
//  - encE/decE = (Wih @ emb_W) with GATE-INTERLEAVED rows: out row c = j*4+gate
//  - encWhhI/decWhhI = Whh rows reordered to the same interleaving
//  - encBI/decBI = biases interleaved; v0bI = dec bias + dec_Wih@dec_input0
// ---------------------------------------------------------------------------
__global__ void fold_kernel(const float* __restrict__ encWih,
                            const float* __restrict__ encWhh,
                            const float* __restrict__ enc_b,
                            const float* __restrict__ decWih,
                            const float* __restrict__ decWhh,
                            const float* __restrict__ dec_b,
                            const float* __restrict__ embW,
                            const float* __restrict__ dec0,
                            float* __restrict__ encE, float* __restrict__ encWhhI,
                            float* __restrict__ encBI,
                            float* __restrict__ decE, float* __restrict__ decWhhI,
                            float* __restrict__ decBI, float* __restrict__ v0bI) {
    const int o = blockIdx.x;            // original row 0..2047 (gate*512 + j)
    const int gate = o >> 9, j = o & 511;
    const int c = j * 4 + gate;          // interleaved row
    const int g = threadIdx.x;           // 0..127
    float se = 0.f, sd = 0.f;
    for (int e = 0; e < Edim; ++e) {
        float w = embW[e * Gdim + g];
        se += encWih[(size_t)o * Edim + e] * w;
        sd += decWih[(size_t)o * Edim + e] * w;
    }
    encE[(size_t)c * Gdim + g] = se;
    decE[(size_t)c * Gdim + g] = sd;
    for (int k = g; k < Hdim; k += Gdim) {
        encWhhI[(size_t)c * Hdim + k] = encWhh[(size_t)o * Hdim + k];
        decWhhI[(size_t)c * Hdim + k] = decWhh[(size_t)o * Hdim + k];
    }
    if (g == 0) {
        encBI[c] = enc_b[o];
        decBI[c] = dec_b[o];
        float s = dec_b[o];
        for (int e = 0; e < Edim; ++e) s += decWih[(size_t)o * Edim + e] * dec0[e];
        v0bI[c] = s;
    }
}

// ---------------------------------------------------------------------------
// Big fused GEMM + LSTM epilogue. 128 threads = 2 waves, block tile 128x64.
// Wave w owns rows w*64..w*64+63 (all 64 cols); lane (ly,lx) has an 8x8 tile
// at rows w*64+ly*8, cols lx*8. All LDS reads are 2-way bank aliased (free).
// Per wave-kk: 64 FMA (128 VALU cyc / 4 SIMDs = 32) vs 4 ds_read_b128
// (~36 cyc on the shared LDS pipe) -> ~85% VALU ceiling.
// acc 64 + frag 16 + staging 24 VGPRs ~= 120 total: fits the 128-VGPR cap
// WITHOUT spilling (round 4's 16x8 tile needed ~175 -> spilled -> 2 GB of
// scratch HBM traffic per dispatch; that was the 870 us regression).
// Grid: dec (32,32)=1024 blocks = 4/CU exact; enc (40,32)=1280 = 5/CU exact.
// Main cols (< split): gates GEMM + LSTM epilogue -> h_out/c_out.
// Aux cols (>= split): K2-only GEMM h @ W3^T + bias3 -> C3 (Wref2 -> u2).
// ---------------------------------------------------------------------------
__global__ __launch_bounds__(128) void gemm_big(
    const float* __restrict__ A1, int lda1, int K1,
    const float* __restrict__ W1,
    const int* __restrict__ gather, int gmul,
    const float* __restrict__ A2, int lda2, int K2,
    const float* __restrict__ W2,
    const float* __restrict__ bias,
    int split,
    const float* __restrict__ W3, const float* __restrict__ bias3,
    float* __restrict__ C3, int ldc3,
    const float* __restrict__ c_in, float* __restrict__ h_out,
    float* __restrict__ c_out, int czero)
{
    __shared__ float As[BK][128];
    __shared__ float Bs[BK][64];
    const int tid = threadIdx.x;
    const int rowBase = blockIdx.y * 128;
    const int colBase = blockIdx.x * 64;
    const bool aux = (colBase >= split);

    const int wv = tid >> 6;
    const int lane = tid & 63;
    const int lx = lane & 7, ly = lane >> 3;
    const int rW = wv * 64 + ly * 8;     // row offset within block tile
    const int cOff = lx * 8;             // col offset within block tile

    // staging: A row 'tid' (4 float4); B row 'tid>>1' half (tid&1) (2 float4)
    const int rb = tid >> 1;
    const int bOff = (tid & 1) * 8;

    size_t g0 = 0;
    if (gather) g0 = (size_t)gather[rowBase + tid] * gmul;
    const float* arow1 = A1 ? (A1 + (size_t)(rowBase + tid) * lda1 + g0) : nullptr;
    const float* arow2 = A2 ? (A2 + (size_t)(rowBase + tid) * lda2) : nullptr;
    const float* brow1 = W1 ? (W1 + (size_t)(colBase + rb) * K1 + bOff) : nullptr;
    const float* brow2 = W2 ? (W2 + (size_t)(colBase + rb) * K2 + bOff) : nullptr;
    const float* brow3 = (aux && W3)
        ? (W3 + (size_t)(colBase - split + rb) * K2 + bOff) : nullptr;

    float4 aR[4], bR[2];
    auto stageA = [&](int kt) {
        const float* p = (kt < K1) ? (arow1 + kt) : (arow2 + (kt - K1));
#pragma unroll
        for (int q = 0; q < 4; ++q) aR[q] = *(const float4*)(p + 4 * q);
    };
    auto stageB = [&](int kt) {
        const float* p;
        if (aux)          p = brow3 + (kt - K1);
        else if (kt < K1) p = brow1 + kt;
        else              p = brow2 + (kt - K1);
        bR[0] = *(const float4*)(p);
        bR[1] = *(const float4*)(p + 4);
    };

    float acc[8][8];
#pragma unroll
    for (int i = 0; i < 8; ++i)
#pragma unroll
        for (int j = 0; j < 8; ++j) acc[i][j] = 0.f;

    const int KT = K1 + K2;
    const int kt0 = aux ? K1 : 0;
    stageA(kt0); stageB(kt0);

    for (int kt = kt0; kt < KT; kt += BK) {
        __syncthreads();
#pragma unroll
        for (int q = 0; q < 4; ++q) {
            As[4 * q + 0][tid] = aR[q].x;
            As[4 * q + 1][tid] = aR[q].y;
            As[4 * q + 2][tid] = aR[q].z;
            As[4 * q + 3][tid] = aR[q].w;
        }
#pragma unroll
        for (int q = 0; q < 2; ++q) {
            Bs[bOff + 4 * q + 0][rb] = bR[q].x;
            Bs[bOff + 4 * q + 1][rb] = bR[q].y;
            Bs[bOff + 4 * q + 2][rb] = bR[q].z;
            Bs[bOff + 4 * q + 3][rb] = bR[q].w;
        }
        __syncthreads();
        if (kt + BK < KT) { stageA(kt + BK); stageB(kt + BK); }

#pragma unroll
        for (int kk = 0; kk < BK; ++kk) {
            float a[8], b[8];
            *(float4*)&a[0] = *(const float4*)&As[kk][rW];
            *(float4*)&a[4] = *(const float4*)&As[kk][rW + 4];
            *(float4*)&b[0] = *(const float4*)&Bs[kk][cOff];
            *(float4*)&b[4] = *(const float4*)&Bs[kk][cOff + 4];
#pragma unroll
            for (int i = 0; i < 8; ++i)
#pragma unroll
                for (int j = 0; j < 8; ++j) acc[i][j] += a[i] * b[j];
        }
    }

    if (!aux) {
        // fused LSTM epilogue; cols are gate-interleaved: col = j*4 + gate
        float bb[8];
        *(float4*)&bb[0] = *(const float4*)(bias + colBase + cOff);
        *(float4*)&bb[4] = *(const float4*)(bias + colBase + cOff + 4);
        const int jBase = (colBase + cOff) >> 2;   // 2 j's per lane
#pragma unroll
        for (int i = 0; i < 8; ++i) {
            const int row = rowBase + rW + i;
#pragma unroll
            for (int jj = 0; jj < 2; ++jj) {
                float gi = acc[i][jj * 4 + 0] + bb[jj * 4 + 0];
                float gf = acc[i][jj * 4 + 1] + bb[jj * 4 + 1];
                float gg = acc[i][jj * 4 + 2] + bb[jj * 4 + 2];
                float go = acc[i][jj * 4 + 3] + bb[jj * 4 + 3];
                float si = 1.f / (1.f + expf(-gi));
                float sf = 1.f / (1.f + expf(-gf));
                float so = 1.f / (1.f + expf(-go));
                const int j = jBase + jj;
                float co = czero ? 0.f : c_in[(size_t)row * Hdim + j];
                float cn = si * tanhf(gg) + sf * co;
                c_out[(size_t)row * Hdim + j] = cn;
                h_out[(size_t)row * Hdim + j] = so * tanhf(cn);
            }
        }
    } else {
        const int cb = colBase - split + cOff;
        float bb[8];
        *(float4*)&bb[0] = *(const float4*)(bias3 + cb);
        *(float4*)&bb[4] = *(const float4*)(bias3 + cb + 4);
#pragma unroll
        for (int i = 0; i < 8; ++i) {
            const int row = rowBase + rW + i;
#pragma unroll
            for (int jj = 0; jj < 2; ++jj) {
                float4 o;
                o.x = acc[i][jj * 4 + 0] + bb[jj * 4 + 0];
                o.y = acc[i][jj * 4 + 1] + bb[jj * 4 + 1];
                o.z = acc[i][jj * 4 + 2] + bb[jj * 4 + 2];
                o.w = acc[i][jj * 4 + 3] + bb[jj * 4 + 3];
                *(float4*)(C3 + (size_t)row * ldc3 + cb + 4 * jj) = o;
            }
        }
    }
}

// ---------------------------------------------------------------------------
// Small GEMM for qp = h @ Wq2^T + bq2  (4096x512, K=512). 64x64 tile, 256
// threads, 2x2 waves, lane 8x8, per-lane 4x4 (proven: 52 VGPR, no spill).
// ---------------------------------------------------------------------------
__global__ __launch_bounds__(256, 4) void gemm_qp(const float* __restrict__ A,
                                                  const float* __restrict__ W,
                                                  const float* __restrict__ bias,
                                                  float* __restrict__ C)
{
    __shared__ float As[BK][64];
    __shared__ float Bs[BK][64];
    const int tid = threadIdx.x;
    const int rowBase = blockIdx.y * 64;
    const int colBase = blockIdx.x * 64;
    const int wv = tid >> 6;
    const int waveX = wv & 1, waveY = wv >> 1;
    const int lane = tid & 63;
    const int lx = lane & 7, ly = lane >> 3;
    const int rOff = waveY * 32 + ly * 4;
    const int cOff = waveX * 32 + lx * 4;

    const int ra = tid & 63;
    const int ka = (tid >> 6) * 4;
    const float* arow = A + (size_t)(rowBase + ra) * Hdim + ka;
    const float* brow = W + (size_t)(colBase + ra) * Hdim + ka;

    float4 aR, bR;
    float acc[4][4];
#pragma unroll
    for (int i = 0; i < 4; ++i)
#pragma unroll
        for (int j = 0; j < 4; ++j) acc[i][j] = 0.f;

    aR = *(const float4*)(arow);
    bR = *(const float4*)(brow);
    for (int kt = 0; kt < Hdim; kt += BK) {
        __syncthreads();
        As[ka + 0][ra] = aR.x; As[ka + 1][ra] = aR.y;
        As[ka + 2][ra] = aR.z; As[ka + 3][ra] = aR.w;
        Bs[ka + 0][ra] = bR.x; Bs[ka + 1][ra] = bR.y;
        Bs[ka + 2][ra] = bR.z; Bs[ka + 3][ra] = bR.w;
        __syncthreads();
        if (kt + BK < Hdim) {
            aR = *(const float4*)(arow + kt + BK);
            bR = *(const float4*)(brow + kt + BK);
        }
#pragma unroll
        for (int kk = 0; kk < BK; ++kk) {
            float4 av = *(const float4*)&As[kk][rOff];
            float4 bv = *(const float4*)&Bs[kk][cOff];
            const float* ap = (const float*)&av;
            const float* bp = (const float*)&bv;
#pragma unroll
            for (int i = 0; i < 4; ++i)
#pragma unroll
                for (int j = 0; j < 4; ++j) acc[i][j] += ap[i] * bp[j];
        }
    }

    float4 bb = *(const float4*)(bias + colBase + cOff);
#pragma unroll
    for (int i = 0; i < 4; ++i) {
        const int row = rowBase + rOff + i;
        float4 o;
        o.x = acc[i][0] + bb.x;
        o.y = acc[i][1] + bb.y;
        o.z = acc[i][2] + bb.z;
        o.w = acc[i][3] + bb.w;
        *(float4*)(C + (size_t)row * Hdim + colBase + cOff) = o;
    }
}

// ---------------------------------------------------------------------------
// Attention + log-softmax + argmax + state update.
// ---------------------------------------------------------------------------
__global__ __launch_bounds__(256) void attn_step(const float* __restrict__ qp,
                                                 const float* __restrict__ u2,
                                                 const float* __restrict__ Vec2,
                                                 float* __restrict__ mask,
                                                 float* __restrict__ ll_ws,
                                                 int* __restrict__ nxt,
                                                 float* __restrict__ out_map,
                                                 float* __restrict__ out_ll,
                                                 int step, int node) {
    const int b = blockIdx.x;
    __shared__ float qpS[Hdim];
    __shared__ float vS[Hdim];
    __shared__ float logitS[Sseq];
    const int tid = threadIdx.x;
    qpS[tid]       = qp[(size_t)b * Hdim + tid];
    qpS[tid + 256] = qp[(size_t)b * Hdim + 256 + tid];
    vS[tid]        = Vec2[tid];
    vS[tid + 256]  = Vec2[256 + tid];
    __syncthreads();

    const int wave = tid >> 6, lane = tid & 63;
    for (int si = 0; si < 4; ++si) {
        int s = wave * 4 + si;
        const float* u2p = u2 + ((size_t)b * Sseq + s) * Hdim;
        float sum = 0.f;
#pragma unroll
        for (int i = 0; i < 8; ++i) {
            int hh = lane + i * 64;
            sum += vS[hh] * tanhf(qpS[hh] + u2p[hh]);
        }
        for (int off = 32; off > 0; off >>= 1) sum += __shfl_down(sum, off);
        if (lane == 0) {
            float pen = step ? mask[b * Sseq + s] * 1e8f : 0.f;
            logitS[s] = 10.f * sum - pen;
        }
    }
    __syncthreads();

    if (tid == 0) {
        float mx = logitS[0];
        int am = 0;
        for (int s = 1; s < Sseq; ++s)
            if (logitS[s] > mx) { mx = logitS[s]; am = s; }
        float se = 0.f;
        for (int s = 0; s < Sseq; ++s) se += expf(logitS[s] - mx);
        float lp = -logf(se);
        float llv = (step ? ll_ws[b] : 0.f) + lp;
        ll_ws[b] = llv;
        out_ll[b] = llv;
        nxt[b] = am;
        if (step == 0) {
            for (int s = 0; s < Sseq; ++s) mask[b * Sseq + s] = (s == am) ? 1.f : 0.f;
        } else {
            mask[b * Sseq + am] += 1.f;
        }
        out_map[b * Sseq + am] = (float)node;
    }
}

// ---------------------------------------------------------------------------
extern "C" void kernel_launch(void* const* d_in, const int* in_sizes, int n_in,
                              void* d_out, int out_size, void* d_ws, size_t ws_size,
                              hipStream_t stream) {
    const float* x       = (const float*)d_in[0];
    const float* emb_W   = (const float*)d_in[1];
    const float* enc_Wih = (const float*)d_in[2];
    const float* enc_Whh = (const float*)d_in[3];
    const float* enc_b   = (const float*)d_in[4];
    const float* dec_Wih = (const float*)d_in[5];
    const float* dec_Whh = (const float*)d_in[6];
    const float* dec_b   = (const float*)d_in[7];
    const float* Wq2     = (const float*)d_in[8];
    const float* bq2     = (const float*)d_in[9];
    const float* Wref2   = (const float*)d_in[10];
    const float* bref2   = (const float*)d_in[11];
    const float* Vec2    = (const float*)d_in[12];
    const float* dec0    = (const float*)d_in[13];

    // workspace layout (fp32 words) — ~187 MB
    float* ws      = (float*)d_ws;
    float* u2      = ws;                                   // B*S*H
    float* h0      = u2 + (size_t)Bsz * Sseq * Hdim;       // B*H each
    float* c0      = h0 + (size_t)Bsz * Hdim;
    float* h1      = c0 + (size_t)Bsz * Hdim;
    float* c1      = h1 + (size_t)Bsz * Hdim;
    float* qp      = c1 + (size_t)Bsz * Hdim;
    float* mask    = qp + (size_t)Bsz * Hdim;              // B*S
    float* ll      = mask + (size_t)Bsz * Sseq;            // B
    int*   nxt     = (int*)(ll + Bsz);                     // B
    float* encE    = (float*)(nxt + Bsz);                  // 2048*128
    float* decE    = encE + (size_t)H4 * Gdim;
    float* encWhhI = decE + (size_t)H4 * Gdim;             // 2048*512
    float* decWhhI = encWhhI + (size_t)H4 * Hdim;
    float* encBI   = decWhhI + (size_t)H4 * Hdim;          // 2048 each
    float* decBI   = encBI + H4;
    float* v0bI    = decBI + H4;

    float* out_map = (float*)d_out;                        // B*P floats
    float* out_ll  = out_map + (size_t)Bsz * Psteps;       // B floats

    static const int nodes[Psteps] = {0,0,0,0, 1,1,1,1, 2,2,2,2, 3,3,3,3};
    const int BIG = 1 << 30;

    fold_kernel<<<H4, Gdim, 0, stream>>>(enc_Wih, enc_Whh, enc_b,
                                         dec_Wih, dec_Whh, dec_b,
                                         emb_W, dec0,
                                         encE, encWhhI, encBI,
                                         decE, decWhhI, decBI, v0bI);

    // ---- encoder: 16 fused LSTM steps; step t>=1 also computes u2[t-1] ----
    for (int t = 0; t < Sseq; ++t) {
        float* ho = (t & 1) ? h0 : h1;
        float* co = (t & 1) ? c0 : c1;
        const float* hi = (t & 1) ? h1 : h0;
        const float* ci = (t & 1) ? c1 : c0;
        if (t == 0) {
            gemm_big<<<dim3(32, 32), 128, 0, stream>>>(
                x, Sseq * Gdim, Gdim, encE, nullptr, 0,
                nullptr, 0, 0, nullptr,
                encBI, BIG, nullptr, nullptr, nullptr, 0,
                co, ho, co, 1);
        } else {
            gemm_big<<<dim3(40, 32), 128, 0, stream>>>(
                x + t * Gdim, Sseq * Gdim, Gdim, encE, nullptr, 0,
                hi, Hdim, Hdim, encWhhI,
                encBI, H4, Wref2, bref2,
                u2 + (size_t)(t - 1) * Hdim, Sseq * Hdim,
                ci, ho, co, 0);
        }
    }

    // ---- decoder: 16 autoregressive steps; p=0 also computes u2[15] ----
    for (int p = 0; p < Psteps; ++p) {
        const int u = Sseq + p;
        float* ho = (u & 1) ? h0 : h1;
        float* co = (u & 1) ? c0 : c1;
        const float* hi = (u & 1) ? h1 : h0;
        const float* ci = (u & 1) ? c1 : c0;
        if (p == 0) {
            gemm_big<<<dim3(40, 32), 128, 0, stream>>>(
                nullptr, 0, 0, nullptr, nullptr, 0,
                hi, Hdim, Hdim, decWhhI,
                v0bI, H4, Wref2, bref2,
                u2 + (size_t)15 * Hdim, Sseq * Hdim,
                ci, ho, co, 0);
        } else {
            gemm_big<<<dim3(32, 32), 128, 0, stream>>>(
                x, Sseq * Gdim, Gdim, decE, nxt, Gdim,
                hi, Hdim, Hdim, decWhhI,
                decBI, BIG, nullptr, nullptr, nullptr, 0,
                ci, ho, co, 0);
        }
        gemm_qp<<<dim3(8, 64), 256, 0, stream>>>(ho, Wq2, bq2, qp);
        attn_step<<<Bsz, 256, 0, stream>>>(qp, u2, Vec2, mask, ll, nxt,
                                           out_map, out_ll, p, nodes[p]);
    }
}

// Round 6
// 6033.529 us; speedup vs baseline: 4.2649x; 1.0652x over previous
//
#include <hip/hip_runtime.h>
#include <cstddef>

// Problem constants
#define Bsz  4096
#define Sseq 16
#define Gdim 128
#define Edim 256
#define Hdim 512
#define H4   2048
#define Psteps 16
#define BK   16

// ---------------------------------------------------------------------------
// Fold kernel.
//  - encE/decE = (Wih @ emb_W) with GATE-INTERLEAVED rows: out row c = j*4+gate
//  - encWhhI/decWhhI = Whh rows reordered to the same interleaving
//  - encBI/decBI = biases interleaved; v0bI = dec bias + dec_Wih@dec_input0
// ---------------------------------------------------------------------------
__global__ void fold_kernel(const float* __restrict__ encWih,
                            const float* __restrict__ encWhh,
                            const float* __restrict__ enc_b,
                            const float* __restrict__ decWih,
                            const float* __restrict__ decWhh,
                            const float* __restrict__ dec_b,
                            const float* __restrict__ embW,
                            const float* __restrict__ dec0,
                            float* __restrict__ encE, float* __restrict__ encWhhI,
                            float* __restrict__ encBI,
                            float* __restrict__ decE, float* __restrict__ decWhhI,
                            float* __restrict__ decBI, float* __restrict__ v0bI) {
    const int o = blockIdx.x;            // original row 0..2047 (gate*512 + j)
    const int gate = o >> 9, j = o & 511;
    const int c = j * 4 + gate;          // interleaved row
    const int g = threadIdx.x;           // 0..127
    float se = 0.f, sd = 0.f;
    for (int e = 0; e < Edim; ++e) {
        float w = embW[e * Gdim + g];
        se += encWih[(size_t)o * Edim + e] * w;
        sd += decWih[(size_t)o * Edim + e] * w;
    }
    encE[(size_t)c * Gdim + g] = se;
    decE[(size_t)c * Gdim + g] = sd;
    for (int k = g; k < Hdim; k += Gdim) {
        encWhhI[(size_t)c * Hdim + k] = encWhh[(size_t)o * Hdim + k];
        decWhhI[(size_t)c * Hdim + k] = decWhh[(size_t)o * Hdim + k];
    }
    if (g == 0) {
        encBI[c] = enc_b[o];
        decBI[c] = dec_b[o];
        float s = dec_b[o];
        for (int e = 0; e < Edim; ++e) s += decWih[(size_t)o * Edim + e] * dec0[e];
        v0bI[c] = s;
    }
}

// ---------------------------------------------------------------------------
// Gates GEMM + fused LSTM epilogue. 256 threads = 4 waves (2x2 over a
// 128x128 block tile); each wave 64x64; lane (ly,lx) owns an 8x8 tile.
// LDS intensity: 16 floats read per 64 FMA = 1.0 B/FMA -> ~66% VALU ceiling
// (the round-3 8x4 tile was LDS-capped at 44%). Concurrency fix vs rounds
// 2/5: grid exactly (16,32)=512 blocks = 2 blocks/CU (no ragged tail), 4
// waves/block -> 16 waves/CU potential; DOUBLE-BUFFERED LDS with a single
// barrier per K-tile so staging drains into the idle buffer instead of
// stalling compute at a vmcnt(0)+barrier.
// VGPR budget: 64 acc + 16 stage + 16 frag + addr ~ 120 (no cap -> no spill;
// round 4's 16x8 tile spilled 2 GB/dispatch under the 128-VGPR cap).
// A = [gathered x-part (K1) | h-part (K2)]; W rows gate-interleaved.
// ---------------------------------------------------------------------------
__global__ __launch_bounds__(256) void gemm_big(
    const float* __restrict__ A1, int lda1, int K1,
    const float* __restrict__ W1,
    const int* __restrict__ gather, int gmul,
    const float* __restrict__ A2, int lda2, int K2,
    const float* __restrict__ W2,
    const float* __restrict__ bias,
    const float* __restrict__ c_in, float* __restrict__ h_out,
    float* __restrict__ c_out, int czero)
{
    __shared__ float As[2][BK][128];
    __shared__ float Bs[2][BK][128];
    const int tid = threadIdx.x;
    const int rowBase = blockIdx.y * 128;
    const int colBase = blockIdx.x * 128;

    const int wv = tid >> 6, lane = tid & 63;
    const int waveX = wv & 1, waveY = wv >> 1;
    const int lx = lane & 7, ly = lane >> 3;
    const int rOff = waveY * 64 + ly * 8;
    const int cOff = waveX * 64 + lx * 8;

    // staging: thread t handles row/col (t>>1), k-offset (t&1)*8 (8 floats)
    const int sr = tid >> 1;
    const int sk = (tid & 1) * 8;

    size_t g0 = 0;
    if (gather) g0 = (size_t)gather[rowBase + sr] * gmul;
    const float* arow1 = A1 ? A1 + (size_t)(rowBase + sr) * lda1 + g0 + sk : nullptr;
    const float* arow2 = A2 ? A2 + (size_t)(rowBase + sr) * lda2 + sk : nullptr;
    const float* brow1 = W1 ? W1 + (size_t)(colBase + sr) * K1 + sk : nullptr;
    const float* brow2 = W2 ? W2 + (size_t)(colBase + sr) * K2 + sk : nullptr;

    float4 aR[2], bR[2];
    auto stage = [&](int kt) {
        const float* pa = (kt < K1) ? (arow1 + kt) : (arow2 + (kt - K1));
        const float* pb = (kt < K1) ? (brow1 + kt) : (brow2 + (kt - K1));
        aR[0] = *(const float4*)(pa);
        aR[1] = *(const float4*)(pa + 4);
        bR[0] = *(const float4*)(pb);
        bR[1] = *(const float4*)(pb + 4);
    };
    auto commit = [&](int buf) {
#pragma unroll
        for (int q = 0; q < 2; ++q) {
            const float* av = (const float*)&aR[q];
            const float* bv = (const float*)&bR[q];
#pragma unroll
            for (int j = 0; j < 4; ++j) {
                As[buf][sk + 4 * q + j][sr] = av[j];   // banks: 2-way alias, free
                Bs[buf][sk + 4 * q + j][sr] = bv[j];
            }
        }
    };

    float acc[8][8];
#pragma unroll
    for (int i = 0; i < 8; ++i)
#pragma unroll
        for (int j = 0; j < 8; ++j) acc[i][j] = 0.f;

    const int KT = K1 + K2;
    stage(0);
    commit(0);
    __syncthreads();
    int cur = 0;

    for (int kt = 0; kt < KT; kt += BK) {
        const bool more = (kt + BK) < KT;
        if (more) stage(kt + BK);           // global loads in flight over FMAs
#pragma unroll
        for (int kk = 0; kk < BK; ++kk) {
            float a[8], b[8];
            *(float4*)&a[0] = *(const float4*)&As[cur][kk][rOff];
            *(float4*)&a[4] = *(const float4*)&As[cur][kk][rOff + 4];
            *(float4*)&b[0] = *(const float4*)&Bs[cur][kk][cOff];
            *(float4*)&b[4] = *(const float4*)&Bs[cur][kk][cOff + 4];
#pragma unroll
            for (int i = 0; i < 8; ++i)
#pragma unroll
                for (int j = 0; j < 8; ++j) acc[i][j] += a[i] * b[j];
        }
        if (more) {
            commit(cur ^ 1);                // write the idle buffer
            __syncthreads();                // single barrier per K-tile
            cur ^= 1;
        }
    }

    // fused LSTM epilogue; cols gate-interleaved: col = j*4 + gate
    float bb[8];
    *(float4*)&bb[0] = *(const float4*)(bias + colBase + cOff);
    *(float4*)&bb[4] = *(const float4*)(bias + colBase + cOff + 4);
    const int jBase = (colBase + cOff) >> 2;   // 2 j's per lane
#pragma unroll
    for (int i = 0; i < 8; ++i) {
        const int row = rowBase + rOff + i;
#pragma unroll
        for (int jj = 0; jj < 2; ++jj) {
            float gi = acc[i][jj * 4 + 0] + bb[jj * 4 + 0];
            float gf = acc[i][jj * 4 + 1] + bb[jj * 4 + 1];
            float gg = acc[i][jj * 4 + 2] + bb[jj * 4 + 2];
            float go = acc[i][jj * 4 + 3] + bb[jj * 4 + 3];
            float si = 1.f / (1.f + expf(-gi));
            float sf = 1.f / (1.f + expf(-gf));
            float so = 1.f / (1.f + expf(-go));
            const int j = jBase + jj;
            float co = czero ? 0.f : c_in[(size_t)row * Hdim + j];
            float cn = si * tanhf(gg) + sf * co;
            c_out[(size_t)row * Hdim + j] = cn;
            h_out[(size_t)row * Hdim + j] = so * tanhf(cn);
        }
    }
}

// ---------------------------------------------------------------------------
// Small GEMM: C = A @ W^T + bias  (4096 x 512, K=512), parametrized ldc.
// 64x64 tile, 256 threads, 2x2 waves, lane 8x8, per-lane 4x4 (52 VGPR,
// proven). Grid (8,64) = 512 blocks = 2/CU exact. Used for u2 (Wref2) and
// qp (Wq2) projections.
// ---------------------------------------------------------------------------
__global__ __launch_bounds__(256, 4) void gemm_sm(const float* __restrict__ A,
                                                  const float* __restrict__ W,
                                                  const float* __restrict__ bias,
                                                  float* __restrict__ C, int ldc)
{
    __shared__ float As[BK][64];
    __shared__ float Bs[BK][64];
    const int tid = threadIdx.x;
    const int rowBase = blockIdx.y * 64;
    const int colBase = blockIdx.x * 64;
    const int wv = tid >> 6;
    const int waveX = wv & 1, waveY = wv >> 1;
    const int lane = tid & 63;
    const int lx = lane & 7, ly = lane >> 3;
    const int rOff = waveY * 32 + ly * 4;
    const int cOff = waveX * 32 + lx * 4;

    const int ra = tid & 63;
    const int ka = (tid >> 6) * 4;
    const float* arow = A + (size_t)(rowBase + ra) * Hdim + ka;
    const float* brow = W + (size_t)(colBase + ra) * Hdim + ka;

    float4 aR, bR;
    float acc[4][4];
#pragma unroll
    for (int i = 0; i < 4; ++i)
#pragma unroll
        for (int j = 0; j < 4; ++j) acc[i][j] = 0.f;

    aR = *(const float4*)(arow);
    bR = *(const float4*)(brow);
    for (int kt = 0; kt < Hdim; kt += BK) {
        __syncthreads();
        As[ka + 0][ra] = aR.x; As[ka + 1][ra] = aR.y;
        As[ka + 2][ra] = aR.z; As[ka + 3][ra] = aR.w;
        Bs[ka + 0][ra] = bR.x; Bs[ka + 1][ra] = bR.y;
        Bs[ka + 2][ra] = bR.z; Bs[ka + 3][ra] = bR.w;
        __syncthreads();
        if (kt + BK < Hdim) {
            aR = *(const float4*)(arow + kt + BK);
            bR = *(const float4*)(brow + kt + BK);
        }
#pragma unroll
        for (int kk = 0; kk < BK; ++kk) {
            float4 av = *(const float4*)&As[kk][rOff];
            float4 bv = *(const float4*)&Bs[kk][cOff];
            const float* ap = (const float*)&av;
            const float* bp = (const float*)&bv;
#pragma unroll
            for (int i = 0; i < 4; ++i)
#pragma unroll
                for (int j = 0; j < 4; ++j) acc[i][j] += ap[i] * bp[j];
        }
    }

    float4 bb = *(const float4*)(bias + colBase + cOff);
#pragma unroll
    for (int i = 0; i < 4; ++i) {
        const int row = rowBase + rOff + i;
        float4 o;
        o.x = acc[i][0] + bb.x;
        o.y = acc[i][1] + bb.y;
        o.z = acc[i][2] + bb.z;
        o.w = acc[i][3] + bb.w;
        *(float4*)(C + (size_t)row * ldc + colBase + cOff) = o;
    }
}

// ---------------------------------------------------------------------------
// Attention + log-softmax + argmax + state update.
// ---------------------------------------------------------------------------
__global__ __launch_bounds__(256) void attn_step(const float* __restrict__ qp,
                                                 const float* __restrict__ u2,
                                                 const float* __restrict__ Vec2,
                                                 float* __restrict__ mask,
                                                 float* __restrict__ ll_ws,
                                                 int* __restrict__ nxt,
                                                 float* __restrict__ out_map,
                                                 float* __restrict__ out_ll,
                                                 int step, int node) {
    const int b = blockIdx.x;
    __shared__ float qpS[Hdim];
    __shared__ float vS[Hdim];
    __shared__ float logitS[Sseq];
    const int tid = threadIdx.x;
    qpS[tid]       = qp[(size_t)b * Hdim + tid];
    qpS[tid + 256] = qp[(size_t)b * Hdim + 256 + tid];
    vS[tid]        = Vec2[tid];
    vS[tid + 256]  = Vec2[256 + tid];
    __syncthreads();

    const int wave = tid >> 6, lane = tid & 63;
    for (int si = 0; si < 4; ++si) {
        int s = wave * 4 + si;
        const float* u2p = u2 + ((size_t)b * Sseq + s) * Hdim;
        float sum = 0.f;
#pragma unroll
        for (int i = 0; i < 8; ++i) {
            int hh = lane + i * 64;
            sum += vS[hh] * tanhf(qpS[hh] + u2p[hh]);
        }
        for (int off = 32; off > 0; off >>= 1) sum += __shfl_down(sum, off);
        if (lane == 0) {
            float pen = step ? mask[b * Sseq + s] * 1e8f : 0.f;
            logitS[s] = 10.f * sum - pen;
        }
    }
    __syncthreads();

    if (tid == 0) {
        float mx = logitS[0];
        int am = 0;
        for (int s = 1; s < Sseq; ++s)
            if (logitS[s] > mx) { mx = logitS[s]; am = s; }
        float se = 0.f;
        for (int s = 0; s < Sseq; ++s) se += expf(logitS[s] - mx);
        float lp = -logf(se);
        float llv = (step ? ll_ws[b] : 0.f) + lp;
        ll_ws[b] = llv;
        out_ll[b] = llv;
        nxt[b] = am;
        if (step == 0) {
            for (int s = 0; s < Sseq; ++s) mask[b * Sseq + s] = (s == am) ? 1.f : 0.f;
        } else {
            mask[b * Sseq + am] += 1.f;
        }
        out_map[b * Sseq + am] = (float)node;
    }
}

// ---------------------------------------------------------------------------
extern "C" void kernel_launch(void* const* d_in, const int* in_sizes, int n_in,
                              void* d_out, int out_size, void* d_ws, size_t ws_size,
                              hipStream_t stream) {
    const float* x       = (const float*)d_in[0];
    const float* emb_W   = (const float*)d_in[1];
    const float* enc_Wih = (const float*)d_in[2];
    const float* enc_Whh = (const float*)d_in[3];
    const float* enc_b   = (const float*)d_in[4];
    const float* dec_Wih = (const float*)d_in[5];
    const float* dec_Whh = (const float*)d_in[6];
    const float* dec_b   = (const float*)d_in[7];
    const float* Wq2     = (const float*)d_in[8];
    const float* bq2     = (const float*)d_in[9];
    const float* Wref2   = (const float*)d_in[10];
    const float* bref2   = (const float*)d_in[11];
    const float* Vec2    = (const float*)d_in[12];
    const float* dec0    = (const float*)d_in[13];

    // workspace layout (fp32 words) — ~187 MB
    float* ws      = (float*)d_ws;
    float* u2      = ws;                                   // B*S*H
    float* h0      = u2 + (size_t)Bsz * Sseq * Hdim;       // B*H each
    float* c0      = h0 + (size_t)Bsz * Hdim;
    float* h1      = c0 + (size_t)Bsz * Hdim;
    float* c1      = h1 + (size_t)Bsz * Hdim;
    float* qp      = c1 + (size_t)Bsz * Hdim;
    float* mask    = qp + (size_t)Bsz * Hdim;              // B*S
    float* ll      = mask + (size_t)Bsz * Sseq;            // B
    int*   nxt     = (int*)(ll + Bsz);                     // B
    float* encE    = (float*)(nxt + Bsz);                  // 2048*128
    float* decE    = encE + (size_t)H4 * Gdim;
    float* encWhhI = decE + (size_t)H4 * Gdim;             // 2048*512
    float* decWhhI = encWhhI + (size_t)H4 * Hdim;
    float* encBI   = decWhhI + (size_t)H4 * Hdim;          // 2048 each
    float* decBI   = encBI + H4;
    float* v0bI    = decBI + H4;

    float* out_map = (float*)d_out;                        // B*P floats
    float* out_ll  = out_map + (size_t)Bsz * Psteps;       // B floats

    static const int nodes[Psteps] = {0,0,0,0, 1,1,1,1, 2,2,2,2, 3,3,3,3};

    fold_kernel<<<H4, Gdim, 0, stream>>>(enc_Wih, enc_Whh, enc_b,
                                         dec_Wih, dec_Whh, dec_b,
                                         emb_W, dec0,
                                         encE, encWhhI, encBI,
                                         decE, decWhhI, decBI, v0bI);

    const dim3 gBig(16, 32);    // 512 blocks = 2/CU exact
    const dim3 gSm(8, 64);      // 512 blocks = 2/CU exact

    // ---- encoder: 16 fused LSTM steps + u2[t] projection of h(t) ----
    for (int t = 0; t < Sseq; ++t) {
        float* ho = (t & 1) ? h0 : h1;
        float* co = (t & 1) ? c0 : c1;
        const float* hi = (t & 1) ? h1 : h0;
        const float* ci = (t & 1) ? c1 : c0;
        if (t == 0) {
            gemm_big<<<gBig, 256, 0, stream>>>(
                x, Sseq * Gdim, Gdim, encE, nullptr, 0,
                nullptr, 0, 0, nullptr,
                encBI, co, ho, co, 1);
        } else {
            gemm_big<<<gBig, 256, 0, stream>>>(
                x + t * Gdim, Sseq * Gdim, Gdim, encE, nullptr, 0,
                hi, Hdim, Hdim, encWhhI,
                encBI, ci, ho, co, 0);
        }
        gemm_sm<<<gSm, 256, 0, stream>>>(ho, Wref2, bref2,
                                         u2 + (size_t)t * Hdim, Sseq * Hdim);
    }

    // ---- decoder: 16 autoregressive steps ----
    for (int p = 0; p < Psteps; ++p) {
        const int u = Sseq + p;
        float* ho = (u & 1) ? h0 : h1;
        float* co = (u & 1) ? c0 : c1;
        const float* hi = (u & 1) ? h1 : h0;
        const float* ci = (u & 1) ? c1 : c0;
        if (p == 0) {
            gemm_big<<<gBig, 256, 0, stream>>>(
                nullptr, 0, 0, nullptr, nullptr, 0,
                hi, Hdim, Hdim, decWhhI,
                v0bI, ci, ho, co, 0);
        } else {
            gemm_big<<<gBig, 256, 0, stream>>>(
                x, Sseq * Gdim, Gdim, decE, nxt, Gdim,
                hi, Hdim, Hdim, decWhhI,
                decBI, ci, ho, co, 0);
        }
        gemm_sm<<<gSm, 256, 0, stream>>>(ho, Wq2, bq2, qp, Hdim);
        attn_step<<<Bsz, 256, 0, stream>>>(qp, u2, Vec2, mask, ll, nxt,
                                           out_map, out_ll, p, nodes[p]);
    }
}

// Round 7
// 5106.957 us; speedup vs baseline: 5.0387x; 1.1814x over previous
//
#include <hip/hip_runtime.h>
#include <cstddef>

// Problem constants
#define Bsz  4096
#define Sseq 16
#define Gdim 128
#define Edim 256
#define Hdim 512
#define H4   2048
#define Psteps 16
#define BK   16

typedef short bfrag8 __attribute__((ext_vector_type(8)));   // 8 bf16 (4 VGPR)
typedef float f32x4  __attribute__((ext_vector_type(4)));   // MFMA acc

// Exact 3-way bf16 split of fp32 (truncation; residuals exactly representable:
// 24 mantissa bits = 8+8+8). a == hi+mid+lo exactly (normal range).
__device__ __forceinline__ void split3(float f, unsigned short& h,
                                       unsigned short& m, unsigned short& l) {
    unsigned u = __float_as_uint(f);
    h = (unsigned short)(u >> 16);
    float r1 = f - __uint_as_float(u & 0xffff0000u);
    unsigned u1 = __float_as_uint(r1);
    m = (unsigned short)(u1 >> 16);
    float r2 = r1 - __uint_as_float(u1 & 0xffff0000u);
    l = (unsigned short)(__float_as_uint(r2) >> 16);
}

// ---------------------------------------------------------------------------
// Fold kernel: gate-interleaved (row c = j*4+gate) weight prep, now emitting
// bf16 hi/mid/lo planes for the MFMA path.
//  - encE/decE planes = (Wih @ emb_W) interleaved, split  (2048 x 128)
//  - encWhh/decWhh planes = Whh rows interleaved, split   (2048 x 512)
//  - encBI/decBI fp32 interleaved biases; v0bI = dec bias + dec_Wih@dec0
// ---------------------------------------------------------------------------
__global__ void fold_kernel(const float* __restrict__ encWih,
                            const float* __restrict__ encWhh,
                            const float* __restrict__ enc_b,
                            const float* __restrict__ decWih,
                            const float* __restrict__ decWhh,
                            const float* __restrict__ dec_b,
                            const float* __restrict__ embW,
                            const float* __restrict__ dec0,
                            unsigned short* __restrict__ encEh,
                            unsigned short* __restrict__ encEm,
                            unsigned short* __restrict__ encEl,
                            unsigned short* __restrict__ encWh,
                            unsigned short* __restrict__ encWm,
                            unsigned short* __restrict__ encWl,
                            unsigned short* __restrict__ decEh,
                            unsigned short* __restrict__ decEm,
                            unsigned short* __restrict__ decEl,
                            unsigned short* __restrict__ decWh,
                            unsigned short* __restrict__ decWm,
                            unsigned short* __restrict__ decWl,
                            float* __restrict__ encBI, float* __restrict__ decBI,
                            float* __restrict__ v0bI) {
    const int o = blockIdx.x;            // original row 0..2047 (gate*512 + j)
    const int gate = o >> 9, j = o & 511;
    const int c = j * 4 + gate;          // interleaved row
    const int g = threadIdx.x;           // 0..127
    float se = 0.f, sd = 0.f;
    for (int e = 0; e < Edim; ++e) {
        float w = embW[e * Gdim + g];
        se += encWih[(size_t)o * Edim + e] * w;
        sd += decWih[(size_t)o * Edim + e] * w;
    }
    unsigned short h, m, l;
    split3(se, h, m, l);
    encEh[(size_t)c * Gdim + g] = h; encEm[(size_t)c * Gdim + g] = m;
    encEl[(size_t)c * Gdim + g] = l;
    split3(sd, h, m, l);
    decEh[(size_t)c * Gdim + g] = h; decEm[(size_t)c * Gdim + g] = m;
    decEl[(size_t)c * Gdim + g] = l;
    for (int k = g; k < Hdim; k += Gdim) {
        split3(encWhh[(size_t)o * Hdim + k], h, m, l);
        encWh[(size_t)c * Hdim + k] = h; encWm[(size_t)c * Hdim + k] = m;
        encWl[(size_t)c * Hdim + k] = l;
        split3(decWhh[(size_t)o * Hdim + k], h, m, l);
        decWh[(size_t)c * Hdim + k] = h; decWm[(size_t)c * Hdim + k] = m;
        decWl[(size_t)c * Hdim + k] = l;
    }
    if (g == 0) {
        encBI[c] = enc_b[o];
        decBI[c] = dec_b[o];
        float s = dec_b[o];
        for (int e = 0; e < Edim; ++e) s += decWih[(size_t)o * Edim + e] * dec0[e];
        v0bI[c] = s;
    }
}

// ---------------------------------------------------------------------------
// MFMA gates GEMM + fused LSTM epilogue, fp32-exact via bf16x6 emulation.
// D[n][m] = sum_k W'[n][k] * act[m][k]  (n = gate-interleaved output channel,
// m = batch row). 16x16x32 bf16 MFMA; A-frag = W' row (lane&15 = n, k =
// quad*8+j, contiguous bf16 -> 16B global load); B-frag = act row (lane&15 =
// m) read as fp32 and split to hi/mid/lo IN VALU (co-issues with MFMA, no
// extra buffers, h stays fp32 for the downstream kernels). 6 MFMAs/pair:
// hi*hi + hi*mid + mid*hi + mid*mid + hi*lo + lo*hi; dropped terms ~2^-24.
// C/D layout (m89-verified): reg r of lane -> row n = base+quad*4+r -> the 4
// regs are exactly gates i,f,g,o of unit j = base/4+quad: epilogue is
// lane-local. No LDS. Block = 4 waves (2x2), tile 128n x 128m; grid
// (32,16) = 512 blocks = 2/CU; ~180 VGPR -> 2 waves/SIMD.
// ---------------------------------------------------------------------------
__global__ __launch_bounds__(256) void gates_mfma(
    const unsigned short* __restrict__ Wh1, const unsigned short* __restrict__ Wm1,
    const unsigned short* __restrict__ Wl1, int K1,
    const float* __restrict__ X, int ldx,
    const int* __restrict__ gather, int gmul,
    const unsigned short* __restrict__ Wh2, const unsigned short* __restrict__ Wm2,
    const unsigned short* __restrict__ Wl2, int K2,
    const float* __restrict__ Hin,
    const float* __restrict__ biasI,
    const float* __restrict__ c_in, float* __restrict__ h_out,
    float* __restrict__ c_out, int czero)
{
    const int tid = threadIdx.x;
    const int wv = tid >> 6, lane = tid & 63;
    const int wm = wv & 1, wn = wv >> 1;
    const int lm = lane & 15, quad = lane >> 4;
    const int nT = blockIdx.y * 128 + wn * 64;   // output-channel tile base
    const int mB = blockIdx.x * 128 + wm * 64;   // batch tile base

    // per-lane activation row pointers (4 m-tiles)
    int mrow[4];
    const float* xr[4];
    const float* hr[4];
#pragma unroll
    for (int tm = 0; tm < 4; ++tm) {
        int m = mB + tm * 16 + lm;
        mrow[tm] = m;
        if (X) {
            size_t off = (size_t)m * ldx;
            if (gather) off += (size_t)gather[m] * gmul;
            xr[tm] = X + off;
        }
        if (Hin) hr[tm] = Hin + (size_t)m * K2;
    }
    // per-lane weight row offsets (4 n-tiles)
    size_t aR1[4], aR2[4];
#pragma unroll
    for (int tn = 0; tn < 4; ++tn) {
        int n = nT + tn * 16 + lm;
        aR1[tn] = (size_t)n * K1;
        aR2[tn] = (size_t)n * K2;
    }

    f32x4 acc[4][4];
#pragma unroll
    for (int i = 0; i < 4; ++i)
#pragma unroll
        for (int j = 0; j < 4; ++j) acc[i][j] = (f32x4){0.f, 0.f, 0.f, 0.f};

    const int KT = K1 + K2;
    for (int kc = 0; kc < KT; kc += 32) {
        const bool inX = kc < K1;
        const int kk = (inX ? kc : kc - K1) + quad * 8;

        bfrag8 ah[4], am[4], al[4];
#pragma unroll
        for (int tn = 0; tn < 4; ++tn) {
            if (inX) {
                ah[tn] = *(const bfrag8*)(Wh1 + aR1[tn] + kk);
                am[tn] = *(const bfrag8*)(Wm1 + aR1[tn] + kk);
                al[tn] = *(const bfrag8*)(Wl1 + aR1[tn] + kk);
            } else {
                ah[tn] = *(const bfrag8*)(Wh2 + aR2[tn] + kk);
                am[tn] = *(const bfrag8*)(Wm2 + aR2[tn] + kk);
                al[tn] = *(const bfrag8*)(Wl2 + aR2[tn] + kk);
            }
        }
#pragma unroll
        for (int tm = 0; tm < 4; ++tm) {
            const float* p = (inX ? xr[tm] : hr[tm]) + kk;
            float a8[8];
            *(float4*)&a8[0] = *(const float4*)(p);
            *(float4*)&a8[4] = *(const float4*)(p + 4);
            bfrag8 bh, bm, bl;
#pragma unroll
            for (int j = 0; j < 8; ++j) {
                unsigned short h, m, l;
                split3(a8[j], h, m, l);
                bh[j] = (short)h; bm[j] = (short)m; bl[j] = (short)l;
            }
#pragma unroll
            for (int tn = 0; tn < 4; ++tn) {
                f32x4 c = acc[tn][tm];
                c = __builtin_amdgcn_mfma_f32_16x16x32_bf16(ah[tn], bl, c, 0, 0, 0);
                c = __builtin_amdgcn_mfma_f32_16x16x32_bf16(al[tn], bh, c, 0, 0, 0);
                c = __builtin_amdgcn_mfma_f32_16x16x32_bf16(am[tn], bm, c, 0, 0, 0);
                c = __builtin_amdgcn_mfma_f32_16x16x32_bf16(ah[tn], bm, c, 0, 0, 0);
                c = __builtin_amdgcn_mfma_f32_16x16x32_bf16(am[tn], bh, c, 0, 0, 0);
                c = __builtin_amdgcn_mfma_f32_16x16x32_bf16(ah[tn], bh, c, 0, 0, 0);
                acc[tn][tm] = c;
            }
        }
    }

    // fused LSTM epilogue: lane's 4 acc regs = gates i,f,g,o of unit j
#pragma unroll
    for (int tn = 0; tn < 4; ++tn) {
        const int nb = nT + tn * 16 + quad * 4;
        float4 bb = *(const float4*)(biasI + nb);
        const int j = nb >> 2;
#pragma unroll
        for (int tm = 0; tm < 4; ++tm) {
            const size_t idx = (size_t)mrow[tm] * Hdim + j;
            float gi = acc[tn][tm][0] + bb.x;
            float gf = acc[tn][tm][1] + bb.y;
            float gg = acc[tn][tm][2] + bb.z;
            float go = acc[tn][tm][3] + bb.w;
            float si = 1.f / (1.f + expf(-gi));
            float sf = 1.f / (1.f + expf(-gf));
            float so = 1.f / (1.f + expf(-go));
            float co = czero ? 0.f : c_in[idx];
            float cn = si * tanhf(gg) + sf * co;
            c_out[idx] = cn;
            h_out[idx] = so * tanhf(cn);
        }
    }
}

// ---------------------------------------------------------------------------
// Small fp32 GEMM: C = A @ W^T + bias (4096x512, K=512). 64x64 tile, 256
// threads, 2x2 waves, per-lane 4x4 (52 VGPR, proven). Grid (8,64)=512=2/CU.
// Used for u2 (Wref2) and qp (Wq2).
// ---------------------------------------------------------------------------
__global__ __launch_bounds__(256, 4) void gemm_sm(const float* __restrict__ A,
                                                  const float* __restrict__ W,
                                                  const float* __restrict__ bias,
                                                  float* __restrict__ C, int ldc)
{
    __shared__ float As[BK][64];
    __shared__ float Bs[BK][64];
    const int tid = threadIdx.x;
    const int rowBase = blockIdx.y * 64;
    const int colBase = blockIdx.x * 64;
    const int wv = tid >> 6;
    const int waveX = wv & 1, waveY = wv >> 1;
    const int lane = tid & 63;
    const int lx = lane & 7, ly = lane >> 3;
    const int rOff = waveY * 32 + ly * 4;
    const int cOff = waveX * 32 + lx * 4;

    const int ra = tid & 63;
    const int ka = (tid >> 6) * 4;
    const float* arow = A + (size_t)(rowBase + ra) * Hdim + ka;
    const float* brow = W + (size_t)(colBase + ra) * Hdim + ka;

    float4 aR, bR;
    float acc[4][4];
#pragma unroll
    for (int i = 0; i < 4; ++i)
#pragma unroll
        for (int j = 0; j < 4; ++j) acc[i][j] = 0.f;

    aR = *(const float4*)(arow);
    bR = *(const float4*)(brow);
    for (int kt = 0; kt < Hdim; kt += BK) {
        __syncthreads();
        As[ka + 0][ra] = aR.x; As[ka + 1][ra] = aR.y;
        As[ka + 2][ra] = aR.z; As[ka + 3][ra] = aR.w;
        Bs[ka + 0][ra] = bR.x; Bs[ka + 1][ra] = bR.y;
        Bs[ka + 2][ra] = bR.z; Bs[ka + 3][ra] = bR.w;
        __syncthreads();
        if (kt + BK < Hdim) {
            aR = *(const float4*)(arow + kt + BK);
            bR = *(const float4*)(brow + kt + BK);
        }
#pragma unroll
        for (int kk = 0; kk < BK; ++kk) {
            float4 av = *(const float4*)&As[kk][rOff];
            float4 bv = *(const float4*)&Bs[kk][cOff];
            const float* ap = (const float*)&av;
            const float* bp = (const float*)&bv;
#pragma unroll
            for (int i = 0; i < 4; ++i)
#pragma unroll
                for (int j = 0; j < 4; ++j) acc[i][j] += ap[i] * bp[j];
        }
    }

    float4 bb = *(const float4*)(bias + colBase + cOff);
#pragma unroll
    for (int i = 0; i < 4; ++i) {
        const int row = rowBase + rOff + i;
        float4 o;
        o.x = acc[i][0] + bb.x;
        o.y = acc[i][1] + bb.y;
        o.z = acc[i][2] + bb.z;
        o.w = acc[i][3] + bb.w;
        *(float4*)(C + (size_t)row * ldc + colBase + cOff) = o;
    }
}

// ---------------------------------------------------------------------------
// Attention + log-softmax + argmax + state update.
// ---------------------------------------------------------------------------
__global__ __launch_bounds__(256) void attn_step(const float* __restrict__ qp,
                                                 const float* __restrict__ u2,
                                                 const float* __restrict__ Vec2,
                                                 float* __restrict__ mask,
                                                 float* __restrict__ ll_ws,
                                                 int* __restrict__ nxt,
                                                 float* __restrict__ out_map,
                                                 float* __restrict__ out_ll,
                                                 int step, int node) {
    const int b = blockIdx.x;
    __shared__ float qpS[Hdim];
    __shared__ float vS[Hdim];
    __shared__ float logitS[Sseq];
    const int tid = threadIdx.x;
    qpS[tid]       = qp[(size_t)b * Hdim + tid];
    qpS[tid + 256] = qp[(size_t)b * Hdim + 256 + tid];
    vS[tid]        = Vec2[tid];
    vS[tid + 256]  = Vec2[256 + tid];
    __syncthreads();

    const int wave = tid >> 6, lane = tid & 63;
    for (int si = 0; si < 4; ++si) {
        int s = wave * 4 + si;
        const float* u2p = u2 + ((size_t)b * Sseq + s) * Hdim;
        float sum = 0.f;
#pragma unroll
        for (int i = 0; i < 8; ++i) {
            int hh = lane + i * 64;
            sum += vS[hh] * tanhf(qpS[hh] + u2p[hh]);
        }
        for (int off = 32; off > 0; off >>= 1) sum += __shfl_down(sum, off);
        if (lane == 0) {
            float pen = step ? mask[b * Sseq + s] * 1e8f : 0.f;
            logitS[s] = 10.f * sum - pen;
        }
    }
    __syncthreads();

    if (tid == 0) {
        float mx = logitS[0];
        int am = 0;
        for (int s = 1; s < Sseq; ++s)
            if (logitS[s] > mx) { mx = logitS[s]; am = s; }
        float se = 0.f;
        for (int s = 0; s < Sseq; ++s) se += expf(logitS[s] - mx);
        float lp = -logf(se);
        float llv = (step ? ll_ws[b] : 0.f) + lp;
        ll_ws[b] = llv;
        out_ll[b] = llv;
        nxt[b] = am;
        if (step == 0) {
            for (int s = 0; s < Sseq; ++s) mask[b * Sseq + s] = (s == am) ? 1.f : 0.f;
        } else {
            mask[b * Sseq + am] += 1.f;
        }
        out_map[b * Sseq + am] = (float)node;
    }
}

// ---------------------------------------------------------------------------
extern "C" void kernel_launch(void* const* d_in, const int* in_sizes, int n_in,
                              void* d_out, int out_size, void* d_ws, size_t ws_size,
                              hipStream_t stream) {
    const float* x       = (const float*)d_in[0];
    const float* emb_W   = (const float*)d_in[1];
    const float* enc_Wih = (const float*)d_in[2];
    const float* enc_Whh = (const float*)d_in[3];
    const float* enc_b   = (const float*)d_in[4];
    const float* dec_Wih = (const float*)d_in[5];
    const float* dec_Whh = (const float*)d_in[6];
    const float* dec_b   = (const float*)d_in[7];
    const float* Wq2     = (const float*)d_in[8];
    const float* bq2     = (const float*)d_in[9];
    const float* Wref2   = (const float*)d_in[10];
    const float* bref2   = (const float*)d_in[11];
    const float* Vec2    = (const float*)d_in[12];
    const float* dec0    = (const float*)d_in[13];

    // workspace layout — ~192 MB
    float* ws      = (float*)d_ws;
    float* u2      = ws;                                   // B*S*H fp32
    float* h0      = u2 + (size_t)Bsz * Sseq * Hdim;       // B*H each
    float* c0      = h0 + (size_t)Bsz * Hdim;
    float* h1      = c0 + (size_t)Bsz * Hdim;
    float* c1      = h1 + (size_t)Bsz * Hdim;
    float* qp      = c1 + (size_t)Bsz * Hdim;
    float* mask    = qp + (size_t)Bsz * Hdim;              // B*S
    float* ll      = mask + (size_t)Bsz * Sseq;            // B
    int*   nxt     = (int*)(ll + Bsz);                     // B
    float* encBI   = (float*)(nxt + Bsz);                  // 2048 each
    float* decBI   = encBI + H4;
    float* v0bI    = decBI + H4;
    // bf16 weight planes (ushort)
    unsigned short* us = (unsigned short*)(v0bI + H4);
    unsigned short* encEh = us;                       us += (size_t)H4 * Gdim;
    unsigned short* encEm = us;                       us += (size_t)H4 * Gdim;
    unsigned short* encEl = us;                       us += (size_t)H4 * Gdim;
    unsigned short* encWh = us;                       us += (size_t)H4 * Hdim;
    unsigned short* encWm = us;                       us += (size_t)H4 * Hdim;
    unsigned short* encWl = us;                       us += (size_t)H4 * Hdim;
    unsigned short* decEh = us;                       us += (size_t)H4 * Gdim;
    unsigned short* decEm = us;                       us += (size_t)H4 * Gdim;
    unsigned short* decEl = us;                       us += (size_t)H4 * Gdim;
    unsigned short* decWh = us;                       us += (size_t)H4 * Hdim;
    unsigned short* decWm = us;                       us += (size_t)H4 * Hdim;
    unsigned short* decWl = us;                       us += (size_t)H4 * Hdim;

    float* out_map = (float*)d_out;                        // B*P floats
    float* out_ll  = out_map + (size_t)Bsz * Psteps;       // B floats

    static const int nodes[Psteps] = {0,0,0,0, 1,1,1,1, 2,2,2,2, 3,3,3,3};

    fold_kernel<<<H4, Gdim, 0, stream>>>(enc_Wih, enc_Whh, enc_b,
                                         dec_Wih, dec_Whh, dec_b,
                                         emb_W, dec0,
                                         encEh, encEm, encEl, encWh, encWm, encWl,
                                         decEh, decEm, decEl, decWh, decWm, decWl,
                                         encBI, decBI, v0bI);

    const dim3 gBig(32, 16);    // m-blocks x n-blocks = 512 = 2/CU
    const dim3 gSm(8, 64);      // 512 blocks = 2/CU

    // ---- encoder: 16 fused LSTM steps + u2[t] projection of h(t) ----
    for (int t = 0; t < Sseq; ++t) {
        float* ho = (t & 1) ? h0 : h1;
        float* co = (t & 1) ? c0 : c1;
        const float* hi = (t & 1) ? h1 : h0;
        const float* ci = (t & 1) ? c1 : c0;
        if (t == 0) {
            gates_mfma<<<gBig, 256, 0, stream>>>(
                encEh, encEm, encEl, Gdim,
                x, Sseq * Gdim, nullptr, 0,
                nullptr, nullptr, nullptr, 0, nullptr,
                encBI, ci, ho, co, 1);
        } else {
            gates_mfma<<<gBig, 256, 0, stream>>>(
                encEh, encEm, encEl, Gdim,
                x + t * Gdim, Sseq * Gdim, nullptr, 0,
                encWh, encWm, encWl, Hdim, hi,
                encBI, ci, ho, co, 0);
        }
        gemm_sm<<<gSm, 256, 0, stream>>>(ho, Wref2, bref2,
                                         u2 + (size_t)t * Hdim, Sseq * Hdim);
    }

    // ---- decoder: 16 autoregressive steps ----
    for (int p = 0; p < Psteps; ++p) {
        const int u = Sseq + p;
        float* ho = (u & 1) ? h0 : h1;
        float* co = (u & 1) ? c0 : c1;
        const float* hi = (u & 1) ? h1 : h0;
        const float* ci = (u & 1) ? c1 : c0;
        if (p == 0) {
            gates_mfma<<<gBig, 256, 0, stream>>>(
                nullptr, nullptr, nullptr, 0,
                nullptr, 0, nullptr, 0,
                decWh, decWm, decWl, Hdim, hi,
                v0bI, ci, ho, co, 0);
        } else {
            gates_mfma<<<gBig, 256, 0, stream>>>(
                decEh, decEm, decEl, Gdim,
                x, Sseq * Gdim, nxt, Gdim,
                decWh, decWm, decWl, Hdim, hi,
                decBI, ci, ho, co, 0);
        }
        gemm_sm<<<gSm, 256, 0, stream>>>(ho, Wq2, bq2, qp, Hdim);
        attn_step<<<Bsz, 256, 0, stream>>>(qp, u2, Vec2, mask, ll, nxt,
                                           out_map, out_ll, p, nodes[p]);
    }
}